// Round 8
// baseline (19.832 us; speedup 1.0000x reference)
//
#include <hip/hip_runtime.h>

#define N_ROWS 16384
#define NBLK 128   // 128 blocks x 4 waves = 512 waves x 32 rows = 16384 rows

__global__ __launch_bounds__(256) void kl_onepass(
        const float* __restrict__ loc_g,
        const float* __restrict__ loc_u,
        const float* __restrict__ scl_g,
        const float* __restrict__ scl_u,
        float* __restrict__ partials,
        unsigned* __restrict__ counter,   // zeroed by memset node each call
        float* __restrict__ out) {
    const int tid = threadIdx.x;
    const int lane = tid & 63;
    const int wave_in_blk = tid >> 6;                     // 0..3
    const int bid = blockIdx.x;
    const int wave_id = (bid << 2) | wave_in_blk;         // 0..511
    const int group = lane >> 2;                          // row within 16-row pass
    const int sub = lane & 3;                             // float4-quad within row

    const float4* gP  = reinterpret_cast<const float4*>(loc_g);
    const float4* uP  = reinterpret_cast<const float4*>(loc_u);
    const float4* sgP = reinterpret_cast<const float4*>(scl_g);
    const float4* suP = reinterpret_cast<const float4*>(scl_u);

    float accS = 0.0f;   // per-lane-group: sum of per-row S over both passes

    #pragma unroll
    for (int p = 0; p < 2; ++p) {
        const int row = (wave_id << 5) + (p << 4) + group;
        const int b4 = row * 16 + sub;

        float4 G[4], U[4], SG[4], SU[4];
        #pragma unroll
        for (int e = 0; e < 4; ++e) {
            G[e]  = gP [b4 + 4 * e];
            SG[e] = sgP[b4 + 4 * e];
            U[e]  = uP [b4 + 4 * e];
            SU[e] = suP[b4 + 4 * e];
        }

        float A = 0.f, Gg = 0.f, G1 = 0.f, P = 0.f, R = 0.f;
        float B = 0.f, Ug = 0.f, U1 = 0.f, Q = 0.f;
        #pragma unroll
        for (int e = 0; e < 4; ++e) {
            const float* gp  = reinterpret_cast<const float*>(&G[e]);
            const float* sgp = reinterpret_cast<const float*>(&SG[e]);
            const float* up  = reinterpret_cast<const float*>(&U[e]);
            const float* sup = reinterpret_cast<const float*>(&SU[e]);
            #pragma unroll
            for (int k = 0; k < 4; ++k) {
                float g = gp[k], sg = sgp[k], u = up[k], su = sup[k];
                float sg2 = sg * sg, su2 = su * su;
                float g2 = g * g, u2 = u * u;
                float a = 0.5f / sg2;
                float b = 0.5f / su2;
                A  += a;         Gg += g * a;   G1 += g;
                P  += sg2 + g2;  R  += g2 * a + u2 * b;
                B  += b;         Ug += u * b;   U1 += u;
                Q  += su2 + u2;
            }
        }

        // Reduce 9 sums across each 4-lane group: 2 butterfly steps.
        #pragma unroll
        for (int off = 1; off < 4; off <<= 1) {
            A  += __shfl_xor(A,  off);
            Gg += __shfl_xor(Gg, off);
            G1 += __shfl_xor(G1, off);
            P  += __shfl_xor(P,  off);
            R  += __shfl_xor(R,  off);
            B  += __shfl_xor(B,  off);
            Ug += __shfl_xor(Ug, off);
            U1 += __shfl_xor(U1, off);
            Q  += __shfl_xor(Q,  off);
        }

        // Per-row pairwise total (replicated across the 4 lanes of the group).
        accS += A * Q + B * P + 64.0f * R - 2.0f * (Gg * U1 + G1 * Ug);
    }

    // Butterfly off=4..32 sums the 16 DISTINCT groups exactly once.
    #pragma unroll
    for (int off = 4; off < 64; off <<= 1) accS += __shfl_xor(accS, off);

    __shared__ float lds[4];
    __shared__ int is_last;
    if (lane == 0) lds[wave_in_blk] = accS;
    __syncthreads();

    // Publish partial; draw a ticket. The block drawing NBLK-1 is temporally
    // last: all other partials are already published (release via fence+atomic).
    if (tid == 0) {
        partials[bid] = lds[0] + lds[1] + lds[2] + lds[3];
        __threadfence();
        unsigned old = __hip_atomic_fetch_add(counter, 1u, __ATOMIC_ACQ_REL,
                                              __HIP_MEMORY_SCOPE_AGENT);
        is_last = (old == NBLK - 1);
    }
    __syncthreads();

    // Winner (exactly one block) reduces all partials. No spin anywhere.
    if (is_last && tid < 64) {
        double s = (double)__hip_atomic_load(&partials[tid], __ATOMIC_ACQUIRE,
                                             __HIP_MEMORY_SCOPE_AGENT)
                 + (double)__hip_atomic_load(&partials[tid + 64], __ATOMIC_ACQUIRE,
                                             __HIP_MEMORY_SCOPE_AGENT);
        // Deterministic fixed-order butterfly across 64 lanes.
        #pragma unroll
        for (int off = 1; off < 64; off <<= 1) s += __shfl_xor(s, off);
        if (tid == 0)
            out[0] = (float)(0.5 * (s / ((double)N_ROWS * 4096.0)) - 0.5);
    }
}

extern "C" void kernel_launch(void* const* d_in, const int* in_sizes, int n_in,
                              void* d_out, int out_size, void* d_ws, size_t ws_size,
                              hipStream_t stream) {
    const float* loc_g = (const float*)d_in[0];   // z_loc_gs   [N,64]
    const float* loc_u = (const float*)d_in[1];   // z_loc_uns  [N,64]
    const float* scl_g = (const float*)d_in[2];   // z_scale_gs [N,64]
    const float* scl_u = (const float*)d_in[3];   // z_scale_uns[N,64]
    float* out = (float*)d_out;
    float* partials = (float*)d_ws;                        // 128 floats
    unsigned* counter = (unsigned*)((char*)d_ws + 1024);   // own cache line

    // Graph-legal 4-byte memset node: counter = 0 every call (poison-safe).
    hipMemsetAsync(counter, 0, sizeof(unsigned), stream);
    kl_onepass<<<NBLK, 256, 0, stream>>>(loc_g, loc_u, scl_g, scl_u,
                                         partials, counter, out);
}

// Round 9
// 14.122 us; speedup vs baseline: 1.4043x; 1.4043x over previous
//
#include <hip/hip_runtime.h>

#define N_ROWS 16384
#define NBLK 64   // 64 blocks x 4 waves = 256 waves x 64 rows = 16384 rows

__global__ __launch_bounds__(256) void kl_stage1(
        const float* __restrict__ loc_g,
        const float* __restrict__ loc_u,
        const float* __restrict__ scl_g,
        const float* __restrict__ scl_u,
        float* __restrict__ partials) {
    const int tid = threadIdx.x;
    const int lane = tid & 63;
    const int wave_in_blk = tid >> 6;                     // 0..3
    const int wave_id = (blockIdx.x << 2) | wave_in_blk;  // 0..255
    const int group = lane >> 2;                          // row within 16-row pass
    const int sub = lane & 3;                             // float4-quad within row

    const float4* gP  = reinterpret_cast<const float4*>(loc_g);
    const float4* uP  = reinterpret_cast<const float4*>(loc_u);
    const float4* sgP = reinterpret_cast<const float4*>(scl_g);
    const float4* suP = reinterpret_cast<const float4*>(scl_u);

    float accS = 0.0f;   // per-lane-group: sum of per-row S over 4 passes

    #pragma unroll
    for (int p = 0; p < 4; ++p) {
        const int row = (wave_id << 6) + (p << 4) + group;
        const int b4 = row * 16 + sub;

        float4 G[4], U[4], SG[4], SU[4];
        #pragma unroll
        for (int e = 0; e < 4; ++e) {
            G[e]  = gP [b4 + 4 * e];
            SG[e] = sgP[b4 + 4 * e];
            U[e]  = uP [b4 + 4 * e];
            SU[e] = suP[b4 + 4 * e];
        }

        float A = 0.f, Gg = 0.f, G1 = 0.f, P = 0.f, R = 0.f;
        float B = 0.f, Ug = 0.f, U1 = 0.f, Q = 0.f;
        #pragma unroll
        for (int e = 0; e < 4; ++e) {
            const float* gp  = reinterpret_cast<const float*>(&G[e]);
            const float* sgp = reinterpret_cast<const float*>(&SG[e]);
            const float* up  = reinterpret_cast<const float*>(&U[e]);
            const float* sup = reinterpret_cast<const float*>(&SU[e]);
            #pragma unroll
            for (int k = 0; k < 4; ++k) {
                float g = gp[k], sg = sgp[k], u = up[k], su = sup[k];
                float sg2 = sg * sg, su2 = su * su;
                float g2 = g * g, u2 = u * u;
                float a = 0.5f / sg2;
                float b = 0.5f / su2;
                A  += a;         Gg += g * a;   G1 += g;
                P  += sg2 + g2;  R  += g2 * a + u2 * b;
                B  += b;         Ug += u * b;   U1 += u;
                Q  += su2 + u2;
            }
        }

        // Reduce 9 sums across each 4-lane group: 2 butterfly steps.
        #pragma unroll
        for (int off = 1; off < 4; off <<= 1) {
            A  += __shfl_xor(A,  off);
            Gg += __shfl_xor(Gg, off);
            G1 += __shfl_xor(G1, off);
            P  += __shfl_xor(P,  off);
            R  += __shfl_xor(R,  off);
            B  += __shfl_xor(B,  off);
            Ug += __shfl_xor(Ug, off);
            U1 += __shfl_xor(U1, off);
            Q  += __shfl_xor(Q,  off);
        }

        // Per-row pairwise total (replicated across the 4 lanes of the group).
        accS += A * Q + B * P + 64.0f * R - 2.0f * (Gg * U1 + G1 * Ug);
    }

    // Butterfly off=4..32 sums the 16 DISTINCT groups exactly once.
    #pragma unroll
    for (int off = 4; off < 64; off <<= 1) accS += __shfl_xor(accS, off);

    __shared__ float lds[4];
    if (lane == 0) lds[wave_in_blk] = accS;
    __syncthreads();
    if (tid == 0)
        partials[blockIdx.x] = lds[0] + lds[1] + lds[2] + lds[3];
}

__global__ void kl_stage2(const float* __restrict__ partials,
                          float* __restrict__ out) {
    double s = (double)partials[threadIdx.x];   // exactly one partial per lane
    #pragma unroll
    for (int off = 1; off < 64; off <<= 1) s += __shfl_xor(s, off);
    if (threadIdx.x == 0)
        out[0] = (float)(0.5 * (s / ((double)N_ROWS * 4096.0)) - 0.5);
}

extern "C" void kernel_launch(void* const* d_in, const int* in_sizes, int n_in,
                              void* d_out, int out_size, void* d_ws, size_t ws_size,
                              hipStream_t stream) {
    const float* loc_g = (const float*)d_in[0];   // z_loc_gs   [N,64]
    const float* loc_u = (const float*)d_in[1];   // z_loc_uns  [N,64]
    const float* scl_g = (const float*)d_in[2];   // z_scale_gs [N,64]
    const float* scl_u = (const float*)d_in[3];   // z_scale_uns[N,64]
    float* out = (float*)d_out;
    float* partials = (float*)d_ws;               // 64 floats

    kl_stage1<<<NBLK, 256, 0, stream>>>(loc_g, loc_u, scl_g, scl_u, partials);
    kl_stage2<<<1, 64, 0, stream>>>(partials, out);
}

// Round 10
// 11.217 us; speedup vs baseline: 1.7680x; 1.2590x over previous
//
#include <hip/hip_runtime.h>

#define N_ROWS 16384
#define NBLK 128   // 128 blocks x 4 waves = 512 waves x 32 rows = 16384 rows

__global__ __launch_bounds__(256) void kl_stage1(
        const float* __restrict__ loc_g,
        const float* __restrict__ loc_u,
        const float* __restrict__ scl_g,
        const float* __restrict__ scl_u,
        float* __restrict__ partials) {
    const int tid = threadIdx.x;
    const int lane = tid & 63;
    const int wave_in_blk = tid >> 6;                     // 0..3
    const int wave_id = (blockIdx.x << 2) | wave_in_blk;  // 0..511
    const int group = lane >> 2;                          // row within 16-row pass
    const int sub = lane & 3;                             // float4-quad within row

    const float4* gP  = reinterpret_cast<const float4*>(loc_g);
    const float4* uP  = reinterpret_cast<const float4*>(loc_u);
    const float4* sgP = reinterpret_cast<const float4*>(scl_g);
    const float4* suP = reinterpret_cast<const float4*>(scl_u);

    float accS = 0.0f;   // per-lane-group: sum of per-row S over both passes

    #pragma unroll
    for (int p = 0; p < 2; ++p) {
        const int row = (wave_id << 5) + (p << 4) + group;
        const int b4 = row * 16 + sub;

        float4 G[4], U[4], SG[4], SU[4];
        #pragma unroll
        for (int e = 0; e < 4; ++e) {
            G[e]  = gP [b4 + 4 * e];
            SG[e] = sgP[b4 + 4 * e];
            U[e]  = uP [b4 + 4 * e];
            SU[e] = suP[b4 + 4 * e];
        }

        float A = 0.f, Gg = 0.f, G1 = 0.f, P = 0.f, R = 0.f;
        float B = 0.f, Ug = 0.f, U1 = 0.f, Q = 0.f;
        #pragma unroll
        for (int e = 0; e < 4; ++e) {
            const float* gp  = reinterpret_cast<const float*>(&G[e]);
            const float* sgp = reinterpret_cast<const float*>(&SG[e]);
            const float* up  = reinterpret_cast<const float*>(&U[e]);
            const float* sup = reinterpret_cast<const float*>(&SU[e]);
            #pragma unroll
            for (int k = 0; k < 4; ++k) {
                float g = gp[k], sg = sgp[k], u = up[k], su = sup[k];
                float sg2 = sg * sg, su2 = su * su;
                float g2 = g * g, u2 = u * u;
                float a = 0.5f / sg2;
                float b = 0.5f / su2;
                A  += a;         Gg += g * a;   G1 += g;
                P  += sg2 + g2;  R  += g2 * a + u2 * b;
                B  += b;         Ug += u * b;   U1 += u;
                Q  += su2 + u2;
            }
        }

        // Reduce 9 sums across each 4-lane group: 2 butterfly steps.
        #pragma unroll
        for (int off = 1; off < 4; off <<= 1) {
            A  += __shfl_xor(A,  off);
            Gg += __shfl_xor(Gg, off);
            G1 += __shfl_xor(G1, off);
            P  += __shfl_xor(P,  off);
            R  += __shfl_xor(R,  off);
            B  += __shfl_xor(B,  off);
            Ug += __shfl_xor(Ug, off);
            U1 += __shfl_xor(U1, off);
            Q  += __shfl_xor(Q,  off);
        }

        // Per-row pairwise total (replicated across the 4 lanes of the group).
        accS += A * Q + B * P + 64.0f * R - 2.0f * (Gg * U1 + G1 * Ug);
    }

    // Butterfly off=4..32 sums the 16 DISTINCT groups exactly once.
    #pragma unroll
    for (int off = 4; off < 64; off <<= 1) accS += __shfl_xor(accS, off);

    __shared__ float lds[4];
    if (lane == 0) lds[wave_in_blk] = accS;
    __syncthreads();
    if (tid == 0)
        partials[blockIdx.x] = lds[0] + lds[1] + lds[2] + lds[3];
}

__global__ void kl_stage2(const float* __restrict__ partials,
                          float* __restrict__ out) {
    double s = (double)partials[threadIdx.x] + (double)partials[threadIdx.x + 64];
    #pragma unroll
    for (int off = 1; off < 64; off <<= 1) s += __shfl_xor(s, off);
    if (threadIdx.x == 0)
        out[0] = (float)(0.5 * (s / ((double)N_ROWS * 4096.0)) - 0.5);
}

extern "C" void kernel_launch(void* const* d_in, const int* in_sizes, int n_in,
                              void* d_out, int out_size, void* d_ws, size_t ws_size,
                              hipStream_t stream) {
    const float* loc_g = (const float*)d_in[0];   // z_loc_gs   [N,64]
    const float* loc_u = (const float*)d_in[1];   // z_loc_uns  [N,64]
    const float* scl_g = (const float*)d_in[2];   // z_scale_gs [N,64]
    const float* scl_u = (const float*)d_in[3];   // z_scale_uns[N,64]
    float* out = (float*)d_out;
    float* partials = (float*)d_ws;               // 128 floats

    kl_stage1<<<NBLK, 256, 0, stream>>>(loc_g, loc_u, scl_g, scl_u, partials);
    kl_stage2<<<1, 64, 0, stream>>>(partials, out);
}